// Round 9
// baseline (238.686 us; speedup 1.0000x reference)
//
#include <hip/hip_runtime.h>
#include <hip/hip_cooperative_groups.h>

namespace cg = cooperative_groups;

// out = A @ ( d[:,None] * (B @ h_a) + h_b )
//   h_a = relu(x_a @ W_a + b_a), h_b = relu(x_b @ W_b + b_b)
//   A = scatter(edge_ab) [Na,Nb], B = scatter(edge_ba) [Nb,Na]
//   deg = colcount(A) + rowcount(B); d = 1/deg (0 where deg==0)
// Primary: ONE cooperative kernel (512 blocks x 256 = 2 blocks/CU, guaranteed
// co-residency headroom), 4 phases split by grid.sync():
//   P0: zero counters + W -> MFMA fragment layout
//   P1: per block: one dual-MFMA projection tile, then a 512-edge bucketize chunk
//   P2: u = d * (B @ h_a) + h_b       (bucket gather, norm epilogue)
//   P3: out = A @ u                   (bucket gather)
// Fallback (if hipLaunchCooperativeKernel errors): the proven 4-kernel pipeline.

#define D_FEAT 128
#define F_IN 512
#define BCAP 256
#define NROW 4096  // Na == Nb == 4096

using short8 = __attribute__((ext_vector_type(8))) short;
using f32x4  = __attribute__((ext_vector_type(4))) float;

struct Params {
    const float* xa; const float* Wa; const float* ba;
    const float* xb; const float* Wb; const float* bb;
    const int* ab_row; const int* ab_col;
    const int* ba_row; const int* ba_col;
    short* WfA; short* WfB;
    float* ha; float* hb; float* u;
    int* cnt_ab; int* cnt_ba; int* degc;   // contiguous, zeroed in P0
    int* buck_ab; int* buck_ba;
    float* out;
    int Eab; int Eba;
};

__device__ inline short f2bf(float f) {
    unsigned u = __builtin_bit_cast(unsigned, f);
    unsigned r = (u + 0x7FFFu + ((u >> 16) & 1u)) >> 16;
    return (short)r;
}

// ---- W pre-swizzle element: Wf[t][c][lane][e] <- W[k][col] ----------------
//   k = t*32 + (lane>>4)*8 + e, col = c*16 + (lane&15)
__device__ inline void wprep_item(int g0, const Params& P) {
    const float* W = (g0 < 8192) ? P.Wa : P.Wb;
    short* Wf = (g0 < 8192) ? P.WfA : P.WfB;
    int i = g0 & 8191;
    int l = i & 63;
    int c = (i >> 6) & 7;
    int t = i >> 9;  // 0..15
    int col = c * 16 + (l & 15);
    int kbase = t * 32 + (l >> 4) * 8;
    short8 o;
#pragma unroll
    for (int e = 0; e < 8; ++e) o[e] = f2bf(W[(size_t)(kbase + e) * D_FEAT + col]);
    *(short8*)(Wf + (size_t)i * 8) = o;
}

// ---- MFMA projection tile: h[row0..row0+16) = relu(x @ W + b) -------------
// 4 waves K-split (wave w owns K in [w*128, w*128+128)).
__device__ inline void gemm_tile(int blk, int tid, const Params& P,
                                 float red[4][16][132]) {
    const float* x; const short* Wf; const float* bias; float* h;
    if (blk < 256) { x = P.xa; Wf = P.WfA; bias = P.ba; h = P.ha; }
    else { blk -= 256; x = P.xb; Wf = P.WfB; bias = P.bb; h = P.hb; }
    const int row0 = blk * 16;
    const int w = tid >> 6;
    const int l = tid & 63;
    const int lr = l & 15;   // A-row / C-col within tile
    const int lk = l >> 4;   // k-subgroup / C-row-group

    f32x4 acc[8];
#pragma unroll
    for (int c = 0; c < 8; ++c) acc[c] = (f32x4){0.f, 0.f, 0.f, 0.f};

    const float* xrow = x + (size_t)(row0 + lr) * F_IN;
#pragma unroll
    for (int ks = 0; ks < 4; ++ks) {
        const int t = w * 4 + ks;
        const int k0 = t * 32 + lk * 8;
        float4 xf0 = *(const float4*)(xrow + k0);
        float4 xf1 = *(const float4*)(xrow + k0 + 4);
        short8 afr;
        afr[0] = f2bf(xf0.x); afr[1] = f2bf(xf0.y);
        afr[2] = f2bf(xf0.z); afr[3] = f2bf(xf0.w);
        afr[4] = f2bf(xf1.x); afr[5] = f2bf(xf1.y);
        afr[6] = f2bf(xf1.z); afr[7] = f2bf(xf1.w);
        const short8* wfp = (const short8*)Wf + ((size_t)t * 8 * 64 + l);
#pragma unroll
        for (int c = 0; c < 8; ++c) {
            short8 bfr = wfp[c * 64];
            acc[c] = __builtin_amdgcn_mfma_f32_16x16x32_bf16(afr, bfr, acc[c], 0, 0, 0);
        }
    }

#pragma unroll
    for (int c = 0; c < 8; ++c)
#pragma unroll
        for (int r = 0; r < 4; ++r)
            red[w][lk * 4 + r][c * 16 + lr] = acc[c][r];
    __syncthreads();

#pragma unroll
    for (int q = 0; q < 2; ++q) {
        int fi = tid * 2 + q;          // 0..511
        int r = fi >> 5;               // 0..15
        int c4 = fi & 31;              // float4 col index
        float4 s0 = *(const float4*)&red[0][r][c4 * 4];
        float4 s1 = *(const float4*)&red[1][r][c4 * 4];
        float4 s2 = *(const float4*)&red[2][r][c4 * 4];
        float4 s3 = *(const float4*)&red[3][r][c4 * 4];
        float4 bv = ((const float4*)bias)[c4];
        float4 o;
        o.x = fmaxf(s0.x + s1.x + s2.x + s3.x + bv.x, 0.0f);
        o.y = fmaxf(s0.y + s1.y + s2.y + s3.y + bv.y, 0.0f);
        o.z = fmaxf(s0.z + s1.z + s2.z + s3.z + bv.z, 0.0f);
        o.w = fmaxf(s0.w + s1.w + s2.w + s3.w + bv.w, 0.0f);
        ((float4*)(h + (size_t)(row0 + r) * D_FEAT))[c4] = o;
    }
}

// ---- one edge insert --------------------------------------------------------
__device__ inline void edge_item(int g, const Params& P) {
    if (g < P.Eab) {
        int r = P.ab_row[g], c = P.ab_col[g];
        int p = atomicAdd(&P.cnt_ab[r], 1);
        if (p < BCAP) P.buck_ab[(size_t)r * BCAP + p] = c;
        atomicAdd(&P.degc[c], 1);
    } else if (g < P.Eab + P.Eba) {
        int e = g - P.Eab;
        int r = P.ba_row[e], c = P.ba_col[e];
        int p = atomicAdd(&P.cnt_ba[r], 1);
        if (p < BCAP) P.buck_ba[(size_t)r * BCAP + p] = c;
    }
}

// ---- bucket gather-reduce: dst[r] = (norm? d[r]*: ) sum src[buck[r][..]] (+addv[r])
__device__ inline void gather_row(
    const int* __restrict__ cnt, const int* __restrict__ buck,
    const float* __restrict__ src, float* __restrict__ dst,
    const float* __restrict__ addv, const int* __restrict__ dg0,
    const int* __restrict__ dg1, int r, int lane, bool norm) {
    int n = cnt[r];
    if (n > BCAP) n = BCAP;
    const int* cols = buck + (size_t)r * BCAP;
    const float2* s2 = (const float2*)src;
    float ax = 0.0f, ay = 0.0f;
    int e = 0;
    for (; e + 7 < n; e += 8) {
        int c0 = cols[e],     c1 = cols[e + 1], c2 = cols[e + 2], c3 = cols[e + 3];
        int c4 = cols[e + 4], c5 = cols[e + 5], c6 = cols[e + 6], c7 = cols[e + 7];
        float2 v0 = s2[(size_t)c0 * 64 + lane];
        float2 v1 = s2[(size_t)c1 * 64 + lane];
        float2 v2 = s2[(size_t)c2 * 64 + lane];
        float2 v3 = s2[(size_t)c3 * 64 + lane];
        float2 v4 = s2[(size_t)c4 * 64 + lane];
        float2 v5 = s2[(size_t)c5 * 64 + lane];
        float2 v6 = s2[(size_t)c6 * 64 + lane];
        float2 v7 = s2[(size_t)c7 * 64 + lane];
        ax += (v0.x + v1.x) + (v2.x + v3.x) + ((v4.x + v5.x) + (v6.x + v7.x));
        ay += (v0.y + v1.y) + (v2.y + v3.y) + ((v4.y + v5.y) + (v6.y + v7.y));
    }
    for (; e < n; ++e) {
        int c = cols[e];
        float2 v = s2[(size_t)c * 64 + lane];
        ax += v.x; ay += v.y;
    }
    if (norm) {
        float dgf = (float)(dg0[r] + dg1[r]);
        float inv = dgf > 0.0f ? 1.0f / dgf : 0.0f;
        float2 hbv = ((const float2*)addv)[(size_t)r * 64 + lane];
        ax = ax * inv + hbv.x;
        ay = ay * inv + hbv.y;
    }
    float2 o; o.x = ax; o.y = ay;
    ((float2*)dst)[(size_t)r * 64 + lane] = o;
}

// ================= primary: cooperative mega kernel (512 blocks) ============
__global__ __launch_bounds__(256, 2) void latte_mega(Params P) {
    __shared__ float red[4][16][132];
    cg::grid_group grid = cg::this_grid();
    const int tid = threadIdx.x;
    const int bid = blockIdx.x;
    const int g0 = bid * 256 + tid;   // 0..131071

    // ---- P0: zero counters + W -> fragment layout ----
    if (g0 < 3 * NROW) P.cnt_ab[g0] = 0;   // cnt_ab, cnt_ba, degc contiguous
    if (g0 < 16384) wprep_item(g0, P);
    grid.sync();

    // ---- P1: every block: one MFMA projection tile, then 512 edges ----
    gemm_tile(bid, tid, P, red);
    {
        int base = bid * 512 + tid;
        edge_item(base, P);
        edge_item(base + 256, P);
    }
    grid.sync();

    // ---- P2: u = d * (B @ h_a) + h_b  (8 rows/block) ----
#pragma unroll
    for (int q = 0; q < 2; ++q) {
        int r = bid * 8 + q * 4 + (tid >> 6);
        gather_row(P.cnt_ba, P.buck_ba, P.ha, P.u, P.hb, P.degc, P.cnt_ba,
                   r, tid & 63, true);
    }
    grid.sync();

    // ---- P3: out = A @ u ----
#pragma unroll
    for (int q = 0; q < 2; ++q) {
        int r = bid * 8 + q * 4 + (tid >> 6);
        gather_row(P.cnt_ab, P.buck_ab, P.u, P.out, nullptr, nullptr, nullptr,
                   r, tid & 63, false);
    }
}

// ================= fallback: proven 4-kernel pipeline =======================
__global__ __launch_bounds__(256) void w_prep_k(Params P) {
    int g = blockIdx.x * 256 + threadIdx.x;  // 0..16383
    for (int z = g; z < 3 * NROW; z += 16384) P.cnt_ab[z] = 0;
    wprep_item(g, P);
}

__global__ __launch_bounds__(256) void edges_gemm_k(Params P, int nblk_g) {
    int blk = blockIdx.x;
    if (blk >= nblk_g) {
        int g = (blk - nblk_g) * 512 + threadIdx.x;
        edge_item(g, P);
        edge_item(g + 256, P);
        return;
    }
    __shared__ float red[4][16][132];
    gemm_tile(blk, threadIdx.x, P, red);
}

__global__ __launch_bounds__(256) void gather_k(Params P, int which) {
    int r = blockIdx.x * 4 + (threadIdx.x >> 6);
    if (r >= NROW) return;
    if (which == 0)
        gather_row(P.cnt_ba, P.buck_ba, P.ha, P.u, P.hb, P.degc, P.cnt_ba,
                   r, threadIdx.x & 63, true);
    else
        gather_row(P.cnt_ab, P.buck_ab, P.u, P.out, nullptr, nullptr, nullptr,
                   r, threadIdx.x & 63, false);
}

extern "C" void kernel_launch(void* const* d_in, const int* in_sizes, int n_in,
                              void* d_out, int out_size, void* d_ws, size_t ws_size,
                              hipStream_t stream) {
    const float* x_a = (const float*)d_in[0];
    const float* x_b = (const float*)d_in[1];
    const float* W_a = (const float*)d_in[2];
    const float* b_a = (const float*)d_in[3];
    const float* W_b = (const float*)d_in[4];
    const float* b_b = (const float*)d_in[5];
    const int* ei_ab = (const int*)d_in[6];
    const int* ei_ba = (const int*)d_in[7];

    const int D = in_sizes[3];            // 128
    const int Fa = in_sizes[2] / D;       // 512
    const int Na = in_sizes[0] / Fa;      // 4096
    const int Fb = in_sizes[4] / D;       // 512
    const int Nb = in_sizes[1] / Fb;      // 4096
    const int Eab = in_sizes[6] / 2;      // 131072
    const int Eba = in_sizes[7] / 2;      // 131072

    // ---- workspace layout ----
    char* p = (char*)d_ws;
    float* h_a = (float*)p; p += (size_t)Na * D * 4;
    float* h_b = (float*)p; p += (size_t)Nb * D * 4;
    float* u   = (float*)p; p += (size_t)Nb * D * 4;
    int* buck_ab = (int*)p; p += (size_t)Na * BCAP * 4;   // 4 MB
    int* buck_ba = (int*)p; p += (size_t)Nb * BCAP * 4;   // 4 MB
    short* WfA = (short*)p; p += (size_t)Fa * D * 2;      // 128 KB
    short* WfB = (short*)p; p += (size_t)Fb * D * 2;
    int* cnt_ab = (int*)p; p += (size_t)Na * 4;           // zeroed in P0
    int* cnt_ba = (int*)p; p += (size_t)Nb * 4;
    int* degc   = (int*)p; p += (size_t)Nb * 4;

    Params P;
    P.xa = x_a; P.Wa = W_a; P.ba = b_a;
    P.xb = x_b; P.Wb = W_b; P.bb = b_b;
    P.ab_row = ei_ab; P.ab_col = ei_ab + Eab;
    P.ba_row = ei_ba; P.ba_col = ei_ba + Eba;
    P.WfA = WfA; P.WfB = WfB;
    P.ha = h_a; P.hb = h_b; P.u = u;
    P.cnt_ab = cnt_ab; P.cnt_ba = cnt_ba; P.degc = degc;
    P.buck_ab = buck_ab; P.buck_ba = buck_ba;
    P.out = (float*)d_out;
    P.Eab = Eab; P.Eba = Eba;

    void* args[] = { &P };
    hipError_t cerr = hipLaunchCooperativeKernel(
        (const void*)latte_mega, dim3(512), dim3(256), args, 0, stream);
    if (cerr != hipSuccess) {
        // fallback: same math, 4 launches
        w_prep_k<<<64, 256, 0, stream>>>(P);
        int nblk_g = Na / 16 + Nb / 16;                 // 512
        int nEdgeBlk = (Eab + Eba + 511) / 512;         // 512
        edges_gemm_k<<<nblk_g + nEdgeBlk, 256, 0, stream>>>(P, nblk_g);
        gather_k<<<(Nb + 3) / 4, 256, 0, stream>>>(P, 0);
        gather_k<<<(Na + 3) / 4, 256, 0, stream>>>(P, 1);
    }
}

// Round 10
// 51.392 us; speedup vs baseline: 4.6444x; 4.6444x over previous
//
#include <hip/hip_runtime.h>

// out = A @ ( d[:,None] * (B @ h_a) + h_b )
//   h_a = relu(x_a @ W_a + b_a), h_b = relu(x_b @ W_b + b_b)
//   A = scatter(edge_ab) [Na,Nb], B = scatter(edge_ba) [Nb,Na]
//   deg = colcount(A) + rowcount(B); d = 1/deg (0 where deg==0)
// 4-kernel pipeline (coop/grid.sync measured 4x SLOWER -> abandoned):
//   K1 w_prep:     zero counters + W -> MFMA fragment layout
//   K2 edges_gemm: fat kernel = {dual MFMA projection} U {edge bucketize}
//                  h_a written as bf16 (gather source only), h_b as f32
//   K3 gather_u:   u = d * (B @ h_a_bf16) + h_b      (bucket gather, norm)
//   K4 gather_out: out = A @ u                        (bucket gather, f32)
// Buckets are ushort (cols < 4096), capacity 256/row.

#define D_FEAT 128
#define F_IN 512
#define BCAP 256
#define NROW 4096

using short8 = __attribute__((ext_vector_type(8))) short;
using ushort4v = __attribute__((ext_vector_type(4))) unsigned short;
using f32x4  = __attribute__((ext_vector_type(4))) float;

struct Params {
    const float* xa; const float* Wa; const float* ba;
    const float* xb; const float* Wb; const float* bb;
    const int* ab_row; const int* ab_col;
    const int* ba_row; const int* ba_col;
    short* WfA; short* WfB;
    unsigned short* ha_bf;   // [Na][128] bf16
    float* hb; float* u;
    int* cnt_ab; int* cnt_ba; int* degc;   // contiguous, zeroed in K1
    unsigned short* buck_ab; unsigned short* buck_ba;
    float* out;
    int Eab; int Eba;
};

__device__ inline unsigned short f2bf(float f) {
    unsigned u = __builtin_bit_cast(unsigned, f);
    unsigned r = (u + 0x7FFFu + ((u >> 16) & 1u)) >> 16;
    return (unsigned short)r;
}
__device__ inline float bf2f(unsigned short s) {
    unsigned u = ((unsigned)s) << 16;
    return __builtin_bit_cast(float, u);
}

// ---- K1: W pre-swizzle into MFMA B-fragment layout + counter zero ---------
//   Wf[t][c][lane][e]: k = t*32 + (lane>>4)*8 + e, col = c*16 + (lane&15)
__global__ __launch_bounds__(256) void w_prep_k(Params P) {
    int g = blockIdx.x * 256 + threadIdx.x;  // 0..16383
    for (int z = g; z < 3 * NROW; z += 16384) P.cnt_ab[z] = 0;
    const float* W = (g < 8192) ? P.Wa : P.Wb;
    short* Wf = (g < 8192) ? P.WfA : P.WfB;
    int i = g & 8191;
    int l = i & 63;
    int c = (i >> 6) & 7;
    int t = i >> 9;  // 0..15
    int col = c * 16 + (l & 15);
    int kbase = t * 32 + (l >> 4) * 8;
    short8 o;
#pragma unroll
    for (int e = 0; e < 8; ++e) o[e] = (short)f2bf(W[(size_t)(kbase + e) * D_FEAT + col]);
    *(short8*)(Wf + (size_t)i * 8) = o;
}

// ---- K2: fat kernel = dual MFMA GEMM + edge bucketize ---------------------
__global__ __launch_bounds__(256) void edges_gemm_k(Params P, int nblk_g) {
    int blk = blockIdx.x;
    if (blk >= nblk_g) {
        // ---- edge bucketize half: 512 edges/block ----
        int base = (blk - nblk_g) * 512 + threadIdx.x;
#pragma unroll
        for (int q = 0; q < 2; ++q) {
            int g = base + q * 256;
            if (g < P.Eab) {
                int r = P.ab_row[g], c = P.ab_col[g];
                int p = atomicAdd(&P.cnt_ab[r], 1);
                if (p < BCAP) P.buck_ab[(size_t)r * BCAP + p] = (unsigned short)c;
                atomicAdd(&P.degc[c], 1);
            } else if (g < P.Eab + P.Eba) {
                int e = g - P.Eab;
                int r = P.ba_row[e], c = P.ba_col[e];
                int p = atomicAdd(&P.cnt_ba[r], 1);
                if (p < BCAP) P.buck_ba[(size_t)r * BCAP + p] = (unsigned short)c;
            }
        }
        return;
    }
    // ---- MFMA projection half: 16 rows, 4 waves K-split ----
    __shared__ float red[4][16][132];
    const int tid = threadIdx.x;
    const bool isA = (blk < 256);
    const float* x; const short* Wf; const float* bias;
    if (isA) { x = P.xa; Wf = P.WfA; bias = P.ba; }
    else { blk -= 256; x = P.xb; Wf = P.WfB; bias = P.bb; }
    const int row0 = blk * 16;
    const int w = tid >> 6;
    const int l = tid & 63;
    const int lr = l & 15;
    const int lk = l >> 4;

    f32x4 acc[8];
#pragma unroll
    for (int c = 0; c < 8; ++c) acc[c] = (f32x4){0.f, 0.f, 0.f, 0.f};

    const float* xrow = x + (size_t)(row0 + lr) * F_IN;
#pragma unroll
    for (int ks = 0; ks < 4; ++ks) {
        const int t = w * 4 + ks;
        const int k0 = t * 32 + lk * 8;
        float4 xf0 = *(const float4*)(xrow + k0);
        float4 xf1 = *(const float4*)(xrow + k0 + 4);
        short8 afr;
        afr[0] = (short)f2bf(xf0.x); afr[1] = (short)f2bf(xf0.y);
        afr[2] = (short)f2bf(xf0.z); afr[3] = (short)f2bf(xf0.w);
        afr[4] = (short)f2bf(xf1.x); afr[5] = (short)f2bf(xf1.y);
        afr[6] = (short)f2bf(xf1.z); afr[7] = (short)f2bf(xf1.w);
        const short8* wfp = (const short8*)Wf + ((size_t)t * 8 * 64 + l);
#pragma unroll
        for (int c = 0; c < 8; ++c) {
            short8 bfr = wfp[c * 64];
            acc[c] = __builtin_amdgcn_mfma_f32_16x16x32_bf16(afr, bfr, acc[c], 0, 0, 0);
        }
    }

#pragma unroll
    for (int c = 0; c < 8; ++c)
#pragma unroll
        for (int r = 0; r < 4; ++r)
            red[w][lk * 4 + r][c * 16 + lr] = acc[c][r];
    __syncthreads();

#pragma unroll
    for (int q = 0; q < 2; ++q) {
        int fi = tid * 2 + q;          // 0..511
        int r = fi >> 5;               // 0..15
        int c4 = fi & 31;              // float4 col index
        float4 s0 = *(const float4*)&red[0][r][c4 * 4];
        float4 s1 = *(const float4*)&red[1][r][c4 * 4];
        float4 s2 = *(const float4*)&red[2][r][c4 * 4];
        float4 s3 = *(const float4*)&red[3][r][c4 * 4];
        float4 bv = ((const float4*)bias)[c4];
        float ox = fmaxf(s0.x + s1.x + s2.x + s3.x + bv.x, 0.0f);
        float oy = fmaxf(s0.y + s1.y + s2.y + s3.y + bv.y, 0.0f);
        float oz = fmaxf(s0.z + s1.z + s2.z + s3.z + bv.z, 0.0f);
        float ow = fmaxf(s0.w + s1.w + s2.w + s3.w + bv.w, 0.0f);
        if (isA) {
            ushort4v ob;
            ob[0] = f2bf(ox); ob[1] = f2bf(oy); ob[2] = f2bf(oz); ob[3] = f2bf(ow);
            *(ushort4v*)(P.ha_bf + (size_t)(row0 + r) * D_FEAT + c4 * 4) = ob;
        } else {
            float4 o; o.x = ox; o.y = oy; o.z = oz; o.w = ow;
            ((float4*)(P.hb + (size_t)(row0 + r) * D_FEAT))[c4] = o;
        }
    }
}

// ---- K3: u[r] = (1/deg[r] or 0) * sum_{c in B-row r} ha_bf[c] + hb[r] -----
// one wave per row; lane owns feats {2*lane, 2*lane+1}; bf16 source (4B/lane/col).
__global__ __launch_bounds__(256) void gather_u_k(Params P) {
    int r = blockIdx.x * 4 + (threadIdx.x >> 6);
    if (r >= NROW) return;
    int lane = threadIdx.x & 63;
    int n = P.cnt_ba[r];
    if (n > BCAP) n = BCAP;
    const unsigned short* cols = P.buck_ba + (size_t)r * BCAP;
    const unsigned* s2 = (const unsigned*)P.ha_bf;  // 2 bf16 per unsigned
    float ax = 0.0f, ay = 0.0f;
    int e = 0;
    for (; e + 7 < n; e += 8) {
        int c0 = cols[e],     c1 = cols[e + 1], c2 = cols[e + 2], c3 = cols[e + 3];
        int c4 = cols[e + 4], c5 = cols[e + 5], c6 = cols[e + 6], c7 = cols[e + 7];
        unsigned v0 = s2[(size_t)c0 * 64 + lane];
        unsigned v1 = s2[(size_t)c1 * 64 + lane];
        unsigned v2 = s2[(size_t)c2 * 64 + lane];
        unsigned v3 = s2[(size_t)c3 * 64 + lane];
        unsigned v4 = s2[(size_t)c4 * 64 + lane];
        unsigned v5 = s2[(size_t)c5 * 64 + lane];
        unsigned v6 = s2[(size_t)c6 * 64 + lane];
        unsigned v7 = s2[(size_t)c7 * 64 + lane];
        ax += (bf2f((unsigned short)v0) + bf2f((unsigned short)v1)) +
              (bf2f((unsigned short)v2) + bf2f((unsigned short)v3)) +
              ((bf2f((unsigned short)v4) + bf2f((unsigned short)v5)) +
               (bf2f((unsigned short)v6) + bf2f((unsigned short)v7)));
        ay += (bf2f((unsigned short)(v0 >> 16)) + bf2f((unsigned short)(v1 >> 16))) +
              (bf2f((unsigned short)(v2 >> 16)) + bf2f((unsigned short)(v3 >> 16))) +
              ((bf2f((unsigned short)(v4 >> 16)) + bf2f((unsigned short)(v5 >> 16))) +
               (bf2f((unsigned short)(v6 >> 16)) + bf2f((unsigned short)(v7 >> 16))));
    }
    for (; e < n; ++e) {
        unsigned v = s2[(size_t)cols[e] * 64 + lane];
        ax += bf2f((unsigned short)v);
        ay += bf2f((unsigned short)(v >> 16));
    }
    float dgf = (float)(P.degc[r] + P.cnt_ba[r]);
    float inv = dgf > 0.0f ? 1.0f / dgf : 0.0f;
    float2 hbv = ((const float2*)P.hb)[(size_t)r * 64 + lane];
    float2 o;
    o.x = ax * inv + hbv.x;
    o.y = ay * inv + hbv.y;
    ((float2*)P.u)[(size_t)r * 64 + lane] = o;
}

// ---- K4: out[r] = sum_{c in A-row r} u[c]  (f32 source) -------------------
__global__ __launch_bounds__(256) void gather_out_k(Params P) {
    int r = blockIdx.x * 4 + (threadIdx.x >> 6);
    if (r >= NROW) return;
    int lane = threadIdx.x & 63;
    int n = P.cnt_ab[r];
    if (n > BCAP) n = BCAP;
    const unsigned short* cols = P.buck_ab + (size_t)r * BCAP;
    const float2* s2 = (const float2*)P.u;
    float ax = 0.0f, ay = 0.0f;
    int e = 0;
    for (; e + 7 < n; e += 8) {
        int c0 = cols[e],     c1 = cols[e + 1], c2 = cols[e + 2], c3 = cols[e + 3];
        int c4 = cols[e + 4], c5 = cols[e + 5], c6 = cols[e + 6], c7 = cols[e + 7];
        float2 v0 = s2[(size_t)c0 * 64 + lane];
        float2 v1 = s2[(size_t)c1 * 64 + lane];
        float2 v2 = s2[(size_t)c2 * 64 + lane];
        float2 v3 = s2[(size_t)c3 * 64 + lane];
        float2 v4 = s2[(size_t)c4 * 64 + lane];
        float2 v5 = s2[(size_t)c5 * 64 + lane];
        float2 v6 = s2[(size_t)c6 * 64 + lane];
        float2 v7 = s2[(size_t)c7 * 64 + lane];
        ax += (v0.x + v1.x) + (v2.x + v3.x) + ((v4.x + v5.x) + (v6.x + v7.x));
        ay += (v0.y + v1.y) + (v2.y + v3.y) + ((v4.y + v5.y) + (v6.y + v7.y));
    }
    for (; e < n; ++e) {
        float2 v = s2[(size_t)cols[e] * 64 + lane];
        ax += v.x; ay += v.y;
    }
    float2 o; o.x = ax; o.y = ay;
    ((float2*)P.out)[(size_t)r * 64 + lane] = o;
}

extern "C" void kernel_launch(void* const* d_in, const int* in_sizes, int n_in,
                              void* d_out, int out_size, void* d_ws, size_t ws_size,
                              hipStream_t stream) {
    const float* x_a = (const float*)d_in[0];
    const float* x_b = (const float*)d_in[1];
    const float* W_a = (const float*)d_in[2];
    const float* b_a = (const float*)d_in[3];
    const float* W_b = (const float*)d_in[4];
    const float* b_b = (const float*)d_in[5];
    const int* ei_ab = (const int*)d_in[6];
    const int* ei_ba = (const int*)d_in[7];

    const int D = in_sizes[3];            // 128
    const int Fa = in_sizes[2] / D;       // 512
    const int Na = in_sizes[0] / Fa;      // 4096
    const int Fb = in_sizes[4] / D;       // 512
    const int Nb = in_sizes[1] / Fb;      // 4096
    const int Eab = in_sizes[6] / 2;      // 131072
    const int Eba = in_sizes[7] / 2;      // 131072

    // ---- workspace layout ----
    char* p = (char*)d_ws;
    unsigned short* ha_bf = (unsigned short*)p; p += (size_t)Na * D * 2;  // 1 MB
    float* h_b = (float*)p; p += (size_t)Nb * D * 4;                      // 2 MB
    float* u   = (float*)p; p += (size_t)Nb * D * 4;                      // 2 MB
    unsigned short* buck_ab = (unsigned short*)p; p += (size_t)Na * BCAP * 2;  // 2 MB
    unsigned short* buck_ba = (unsigned short*)p; p += (size_t)Nb * BCAP * 2;  // 2 MB
    short* WfA = (short*)p; p += (size_t)Fa * D * 2;                      // 128 KB
    short* WfB = (short*)p; p += (size_t)Fb * D * 2;
    int* cnt_ab = (int*)p; p += (size_t)Na * 4;                           // zeroed in K1
    int* cnt_ba = (int*)p; p += (size_t)Nb * 4;
    int* degc   = (int*)p; p += (size_t)Nb * 4;

    Params P;
    P.xa = x_a; P.Wa = W_a; P.ba = b_a;
    P.xb = x_b; P.Wb = W_b; P.bb = b_b;
    P.ab_row = ei_ab; P.ab_col = ei_ab + Eab;
    P.ba_row = ei_ba; P.ba_col = ei_ba + Eba;
    P.WfA = WfA; P.WfB = WfB;
    P.ha_bf = ha_bf; P.hb = h_b; P.u = u;
    P.cnt_ab = cnt_ab; P.cnt_ba = cnt_ba; P.degc = degc;
    P.buck_ab = buck_ab; P.buck_ba = buck_ba;
    P.out = (float*)d_out;
    P.Eab = Eab; P.Eba = Eba;

    // K1: zero counters + W -> fragment layout
    w_prep_k<<<64, 256, 0, stream>>>(P);

    // K2: fat kernel — projections (blocks 0..511) + edge bucketize
    int nblk_g = Na / 16 + Nb / 16;                 // 512
    int nEdgeBlk = (Eab + Eba + 511) / 512;         // 512
    edges_gemm_k<<<nblk_g + nEdgeBlk, 256, 0, stream>>>(P, nblk_g);

    // K3: u = d * (B @ h_a) + h_b
    gather_u_k<<<(Nb + 3) / 4, 256, 0, stream>>>(P);

    // K4: out = A @ u
    gather_out_k<<<(Na + 3) / 4, 256, 0, stream>>>(P);
}

// Round 11
// 50.119 us; speedup vs baseline: 4.7624x; 1.0254x over previous
//
#include <hip/hip_runtime.h>

// out = A @ ( d[:,None] * (B @ h_a) + h_b )
//   h_a = relu(x_a @ W_a + b_a), h_b = relu(x_b @ W_b + b_b)
//   A = scatter(edge_ab) [Na,Nb], B = scatter(edge_ba) [Nb,Na]
//   deg = colcount(A) + rowcount(B); d = 1/deg (0 where deg==0)
// 4-kernel pipeline (coop/grid.sync measured 4x SLOWER -> abandoned):
//   K1 w_prep:     zero counters + W -> MFMA fragment layout
//   K2 edges_gemm: fat kernel = {dual MFMA projection} U {edge bucketize}
//                  h_a bf16, h_b f32; x loads hoisted 8-deep ahead of MFMA
//   K3 gather_u:   u = d * (B @ h_a_bf16) + h_b   -> u stored bf16
//   K4 gather_out: out = A @ u_bf16               -> f32 output
// Buckets are ushort (cols < 4096), capacity 256/row.

#define D_FEAT 128
#define F_IN 512
#define BCAP 256
#define NROW 4096

using short8 = __attribute__((ext_vector_type(8))) short;
using ushort4v = __attribute__((ext_vector_type(4))) unsigned short;
using f32x4  = __attribute__((ext_vector_type(4))) float;

struct Params {
    const float* xa; const float* Wa; const float* ba;
    const float* xb; const float* Wb; const float* bb;
    const int* ab_row; const int* ab_col;
    const int* ba_row; const int* ba_col;
    short* WfA; short* WfB;
    unsigned short* ha_bf;   // [Na][128] bf16
    float* hb;               // [Nb][128] f32
    unsigned* u_bf;          // [Nb][64]  2x bf16 per word
    int* cnt_ab; int* cnt_ba; int* degc;   // contiguous, zeroed in K1
    unsigned short* buck_ab; unsigned short* buck_ba;
    float* out;
    int Eab; int Eba;
};

__device__ inline unsigned short f2bf(float f) {
    unsigned u = __builtin_bit_cast(unsigned, f);
    unsigned r = (u + 0x7FFFu + ((u >> 16) & 1u)) >> 16;
    return (unsigned short)r;
}
__device__ inline float bf2f(unsigned short s) {
    unsigned u = ((unsigned)s) << 16;
    return __builtin_bit_cast(float, u);
}

// ---- K1: W pre-swizzle into MFMA B-fragment layout + counter zero ---------
//   Wf[t][c][lane][e]: k = t*32 + (lane>>4)*8 + e, col = c*16 + (lane&15)
__global__ __launch_bounds__(256) void w_prep_k(Params P) {
    int g = blockIdx.x * 256 + threadIdx.x;  // 0..16383
    for (int z = g; z < 3 * NROW; z += 16384) P.cnt_ab[z] = 0;
    const float* W = (g < 8192) ? P.Wa : P.Wb;
    short* Wf = (g < 8192) ? P.WfA : P.WfB;
    int i = g & 8191;
    int l = i & 63;
    int c = (i >> 6) & 7;
    int t = i >> 9;  // 0..15
    int col = c * 16 + (l & 15);
    int kbase = t * 32 + (l >> 4) * 8;
    short8 o;
#pragma unroll
    for (int e = 0; e < 8; ++e) o[e] = (short)f2bf(W[(size_t)(kbase + e) * D_FEAT + col]);
    *(short8*)(Wf + (size_t)i * 8) = o;
}

// ---- K2: fat kernel = dual MFMA GEMM + edge bucketize ---------------------
__global__ __launch_bounds__(256) void edges_gemm_k(Params P, int nblk_g) {
    int blk = blockIdx.x;
    if (blk >= nblk_g) {
        // ---- edge bucketize half: 512 edges/block ----
        int base = (blk - nblk_g) * 512 + threadIdx.x;
#pragma unroll
        for (int q = 0; q < 2; ++q) {
            int g = base + q * 256;
            if (g < P.Eab) {
                int r = P.ab_row[g], c = P.ab_col[g];
                int p = atomicAdd(&P.cnt_ab[r], 1);
                if (p < BCAP) P.buck_ab[(size_t)r * BCAP + p] = (unsigned short)c;
                atomicAdd(&P.degc[c], 1);
            } else if (g < P.Eab + P.Eba) {
                int e = g - P.Eab;
                int r = P.ba_row[e], c = P.ba_col[e];
                int p = atomicAdd(&P.cnt_ba[r], 1);
                if (p < BCAP) P.buck_ba[(size_t)r * BCAP + p] = (unsigned short)c;
            }
        }
        return;
    }
    // ---- MFMA projection half: 16 rows, 4 waves K-split ----
    __shared__ float red[4][16][132];
    const int tid = threadIdx.x;
    const bool isA = (blk < 256);
    const float* x; const short* Wf; const float* bias;
    if (isA) { x = P.xa; Wf = P.WfA; bias = P.ba; }
    else { blk -= 256; x = P.xb; Wf = P.WfB; bias = P.bb; }
    const int row0 = blk * 16;
    const int w = tid >> 6;
    const int l = tid & 63;
    const int lr = l & 15;
    const int lk = l >> 4;

    f32x4 acc[8];
#pragma unroll
    for (int c = 0; c < 8; ++c) acc[c] = (f32x4){0.f, 0.f, 0.f, 0.f};

    // hoist ALL x loads (8 independent float4 = 8 outstanding HBM loads)
    const float* xrow = x + (size_t)(row0 + lr) * F_IN;
    float4 xf[8];
#pragma unroll
    for (int ks = 0; ks < 4; ++ks) {
        const int k0 = (w * 4 + ks) * 32 + lk * 8;
        xf[2 * ks]     = *(const float4*)(xrow + k0);
        xf[2 * ks + 1] = *(const float4*)(xrow + k0 + 4);
    }

#pragma unroll
    for (int ks = 0; ks < 4; ++ks) {
        const int t = w * 4 + ks;
        float4 xf0 = xf[2 * ks];
        float4 xf1 = xf[2 * ks + 1];
        short8 afr;
        afr[0] = (short)f2bf(xf0.x); afr[1] = (short)f2bf(xf0.y);
        afr[2] = (short)f2bf(xf0.z); afr[3] = (short)f2bf(xf0.w);
        afr[4] = (short)f2bf(xf1.x); afr[5] = (short)f2bf(xf1.y);
        afr[6] = (short)f2bf(xf1.z); afr[7] = (short)f2bf(xf1.w);
        const short8* wfp = (const short8*)Wf + ((size_t)t * 8 * 64 + l);
#pragma unroll
        for (int c = 0; c < 8; ++c) {
            short8 bfr = wfp[c * 64];
            acc[c] = __builtin_amdgcn_mfma_f32_16x16x32_bf16(afr, bfr, acc[c], 0, 0, 0);
        }
    }

#pragma unroll
    for (int c = 0; c < 8; ++c)
#pragma unroll
        for (int r = 0; r < 4; ++r)
            red[w][lk * 4 + r][c * 16 + lr] = acc[c][r];
    __syncthreads();

#pragma unroll
    for (int q = 0; q < 2; ++q) {
        int fi = tid * 2 + q;          // 0..511
        int r = fi >> 5;               // 0..15
        int c4 = fi & 31;              // float4 col index
        float4 s0 = *(const float4*)&red[0][r][c4 * 4];
        float4 s1 = *(const float4*)&red[1][r][c4 * 4];
        float4 s2 = *(const float4*)&red[2][r][c4 * 4];
        float4 s3 = *(const float4*)&red[3][r][c4 * 4];
        float4 bv = ((const float4*)bias)[c4];
        float ox = fmaxf(s0.x + s1.x + s2.x + s3.x + bv.x, 0.0f);
        float oy = fmaxf(s0.y + s1.y + s2.y + s3.y + bv.y, 0.0f);
        float oz = fmaxf(s0.z + s1.z + s2.z + s3.z + bv.z, 0.0f);
        float ow = fmaxf(s0.w + s1.w + s2.w + s3.w + bv.w, 0.0f);
        if (isA) {
            ushort4v ob;
            ob[0] = f2bf(ox); ob[1] = f2bf(oy); ob[2] = f2bf(oz); ob[3] = f2bf(ow);
            *(ushort4v*)(P.ha_bf + (size_t)(row0 + r) * D_FEAT + c4 * 4) = ob;
        } else {
            float4 o; o.x = ox; o.y = oy; o.z = oz; o.w = ow;
            ((float4*)(P.hb + (size_t)(row0 + r) * D_FEAT))[c4] = o;
        }
    }
}

// ---- K3: u[r] = (1/deg[r] or 0) * sum_{c in B-row r} ha_bf[c] + hb[r] -----
// one wave per row; lane owns feats {2*lane, 2*lane+1}; writes u as bf16 pair.
__global__ __launch_bounds__(256) void gather_u_k(Params P) {
    int r = blockIdx.x * 4 + (threadIdx.x >> 6);
    if (r >= NROW) return;
    int lane = threadIdx.x & 63;
    int n = P.cnt_ba[r];
    if (n > BCAP) n = BCAP;
    const unsigned short* cols = P.buck_ba + (size_t)r * BCAP;
    const unsigned* s2 = (const unsigned*)P.ha_bf;  // 2 bf16 per unsigned
    float ax = 0.0f, ay = 0.0f;
    int e = 0;
    for (; e + 7 < n; e += 8) {
        int c0 = cols[e],     c1 = cols[e + 1], c2 = cols[e + 2], c3 = cols[e + 3];
        int c4 = cols[e + 4], c5 = cols[e + 5], c6 = cols[e + 6], c7 = cols[e + 7];
        unsigned v0 = s2[(size_t)c0 * 64 + lane];
        unsigned v1 = s2[(size_t)c1 * 64 + lane];
        unsigned v2 = s2[(size_t)c2 * 64 + lane];
        unsigned v3 = s2[(size_t)c3 * 64 + lane];
        unsigned v4 = s2[(size_t)c4 * 64 + lane];
        unsigned v5 = s2[(size_t)c5 * 64 + lane];
        unsigned v6 = s2[(size_t)c6 * 64 + lane];
        unsigned v7 = s2[(size_t)c7 * 64 + lane];
        ax += (bf2f((unsigned short)v0) + bf2f((unsigned short)v1)) +
              (bf2f((unsigned short)v2) + bf2f((unsigned short)v3)) +
              ((bf2f((unsigned short)v4) + bf2f((unsigned short)v5)) +
               (bf2f((unsigned short)v6) + bf2f((unsigned short)v7)));
        ay += (bf2f((unsigned short)(v0 >> 16)) + bf2f((unsigned short)(v1 >> 16))) +
              (bf2f((unsigned short)(v2 >> 16)) + bf2f((unsigned short)(v3 >> 16))) +
              ((bf2f((unsigned short)(v4 >> 16)) + bf2f((unsigned short)(v5 >> 16))) +
               (bf2f((unsigned short)(v6 >> 16)) + bf2f((unsigned short)(v7 >> 16))));
    }
    for (; e < n; ++e) {
        unsigned v = s2[(size_t)cols[e] * 64 + lane];
        ax += bf2f((unsigned short)v);
        ay += bf2f((unsigned short)(v >> 16));
    }
    float dgf = (float)(P.degc[r] + P.cnt_ba[r]);
    float inv = dgf > 0.0f ? 1.0f / dgf : 0.0f;
    float2 hbv = ((const float2*)P.hb)[(size_t)r * 64 + lane];
    float ux = ax * inv + hbv.x;
    float uy = ay * inv + hbv.y;
    P.u_bf[(size_t)r * 64 + lane] = (unsigned)f2bf(ux) | ((unsigned)f2bf(uy) << 16);
}

// ---- K4: out[r] = sum_{c in A-row r} u_bf[c]  (f32 output) ----------------
__global__ __launch_bounds__(256) void gather_out_k(Params P) {
    int r = blockIdx.x * 4 + (threadIdx.x >> 6);
    if (r >= NROW) return;
    int lane = threadIdx.x & 63;
    int n = P.cnt_ab[r];
    if (n > BCAP) n = BCAP;
    const unsigned short* cols = P.buck_ab + (size_t)r * BCAP;
    const unsigned* s2 = P.u_bf;
    float ax = 0.0f, ay = 0.0f;
    int e = 0;
    for (; e + 7 < n; e += 8) {
        int c0 = cols[e],     c1 = cols[e + 1], c2 = cols[e + 2], c3 = cols[e + 3];
        int c4 = cols[e + 4], c5 = cols[e + 5], c6 = cols[e + 6], c7 = cols[e + 7];
        unsigned v0 = s2[(size_t)c0 * 64 + lane];
        unsigned v1 = s2[(size_t)c1 * 64 + lane];
        unsigned v2 = s2[(size_t)c2 * 64 + lane];
        unsigned v3 = s2[(size_t)c3 * 64 + lane];
        unsigned v4 = s2[(size_t)c4 * 64 + lane];
        unsigned v5 = s2[(size_t)c5 * 64 + lane];
        unsigned v6 = s2[(size_t)c6 * 64 + lane];
        unsigned v7 = s2[(size_t)c7 * 64 + lane];
        ax += (bf2f((unsigned short)v0) + bf2f((unsigned short)v1)) +
              (bf2f((unsigned short)v2) + bf2f((unsigned short)v3)) +
              ((bf2f((unsigned short)v4) + bf2f((unsigned short)v5)) +
               (bf2f((unsigned short)v6) + bf2f((unsigned short)v7)));
        ay += (bf2f((unsigned short)(v0 >> 16)) + bf2f((unsigned short)(v1 >> 16))) +
              (bf2f((unsigned short)(v2 >> 16)) + bf2f((unsigned short)(v3 >> 16))) +
              ((bf2f((unsigned short)(v4 >> 16)) + bf2f((unsigned short)(v5 >> 16))) +
               (bf2f((unsigned short)(v6 >> 16)) + bf2f((unsigned short)(v7 >> 16))));
    }
    for (; e < n; ++e) {
        unsigned v = s2[(size_t)cols[e] * 64 + lane];
        ax += bf2f((unsigned short)v);
        ay += bf2f((unsigned short)(v >> 16));
    }
    float2 o; o.x = ax; o.y = ay;
    ((float2*)P.out)[(size_t)r * 64 + lane] = o;
}

extern "C" void kernel_launch(void* const* d_in, const int* in_sizes, int n_in,
                              void* d_out, int out_size, void* d_ws, size_t ws_size,
                              hipStream_t stream) {
    const float* x_a = (const float*)d_in[0];
    const float* x_b = (const float*)d_in[1];
    const float* W_a = (const float*)d_in[2];
    const float* b_a = (const float*)d_in[3];
    const float* W_b = (const float*)d_in[4];
    const float* b_b = (const float*)d_in[5];
    const int* ei_ab = (const int*)d_in[6];
    const int* ei_ba = (const int*)d_in[7];

    const int D = in_sizes[3];            // 128
    const int Fa = in_sizes[2] / D;       // 512
    const int Na = in_sizes[0] / Fa;      // 4096
    const int Fb = in_sizes[4] / D;       // 512
    const int Nb = in_sizes[1] / Fb;      // 4096
    const int Eab = in_sizes[6] / 2;      // 131072
    const int Eba = in_sizes[7] / 2;      // 131072

    // ---- workspace layout ----
    char* p = (char*)d_ws;
    unsigned short* ha_bf = (unsigned short*)p; p += (size_t)Na * D * 2;  // 1 MB
    float* h_b = (float*)p; p += (size_t)Nb * D * 4;                      // 2 MB
    unsigned* u_bf = (unsigned*)p; p += (size_t)Nb * (D / 2) * 4;         // 1 MB
    unsigned short* buck_ab = (unsigned short*)p; p += (size_t)Na * BCAP * 2;  // 2 MB
    unsigned short* buck_ba = (unsigned short*)p; p += (size_t)Nb * BCAP * 2;  // 2 MB
    short* WfA = (short*)p; p += (size_t)Fa * D * 2;                      // 128 KB
    short* WfB = (short*)p; p += (size_t)Fb * D * 2;
    int* cnt_ab = (int*)p; p += (size_t)Na * 4;                           // zeroed in K1
    int* cnt_ba = (int*)p; p += (size_t)Nb * 4;
    int* degc   = (int*)p; p += (size_t)Nb * 4;

    Params P;
    P.xa = x_a; P.Wa = W_a; P.ba = b_a;
    P.xb = x_b; P.Wb = W_b; P.bb = b_b;
    P.ab_row = ei_ab; P.ab_col = ei_ab + Eab;
    P.ba_row = ei_ba; P.ba_col = ei_ba + Eba;
    P.WfA = WfA; P.WfB = WfB;
    P.ha_bf = ha_bf; P.hb = h_b; P.u_bf = u_bf;
    P.cnt_ab = cnt_ab; P.cnt_ba = cnt_ba; P.degc = degc;
    P.buck_ab = buck_ab; P.buck_ba = buck_ba;
    P.out = (float*)d_out;
    P.Eab = Eab; P.Eba = Eba;

    // K1: zero counters + W -> fragment layout
    w_prep_k<<<64, 256, 0, stream>>>(P);

    // K2: fat kernel — projections (blocks 0..511) + edge bucketize
    int nblk_g = Na / 16 + Nb / 16;                 // 512
    int nEdgeBlk = (Eab + Eba + 511) / 512;         // 512
    edges_gemm_k<<<nblk_g + nEdgeBlk, 256, 0, stream>>>(P, nblk_g);

    // K3: u = d * (B @ h_a) + h_b   (bf16 out)
    gather_u_k<<<(Nb + 3) / 4, 256, 0, stream>>>(P);

    // K4: out = A @ u
    gather_out_k<<<(Na + 3) / 4, 256, 0, stream>>>(P);
}

// Round 12
// 46.763 us; speedup vs baseline: 5.1041x; 1.0718x over previous
//
#include <hip/hip_runtime.h>

// out = A @ ( d[:,None] * (B @ h_a) + h_b )
//   h_a = relu(x_a @ W_a + b_a), h_b = relu(x_b @ W_b + b_b)
//   A = scatter(edge_ab) [Na,Nb], B = scatter(edge_ba) [Nb,Na]
//   deg = colcount(A) + rowcount(B); d = 1/deg (0 where deg==0)
// 4-kernel pipeline (coop/grid.sync measured 4x SLOWER -> abandoned):
//   K1 w_prep:     zero counters + W -> MFMA fragment layout
//   K2 edges_gemm: fat kernel = {dual MFMA projection} U {edge bucketize}
//   K3 gather_u:   u = d * (B @ h_a_bf16) + h_b   -> u stored bf16
//   K4 gather_out: out = A @ u_bf16               -> f32 output
// Gathers: 16-deep unroll, uniform loads hoisted ahead of the loop.

#define D_FEAT 128
#define F_IN 512
#define BCAP 256
#define NROW 4096

using short8 = __attribute__((ext_vector_type(8))) short;
using ushort4v = __attribute__((ext_vector_type(4))) unsigned short;
using f32x4  = __attribute__((ext_vector_type(4))) float;

struct Params {
    const float* xa; const float* Wa; const float* ba;
    const float* xb; const float* Wb; const float* bb;
    const int* ab_row; const int* ab_col;
    const int* ba_row; const int* ba_col;
    short* WfA; short* WfB;
    unsigned short* ha_bf;   // [Na][128] bf16
    float* hb;               // [Nb][128] f32
    unsigned* u_bf;          // [Nb][64]  2x bf16 per word
    int* cnt_ab; int* cnt_ba; int* degc;   // contiguous, zeroed in K1
    unsigned short* buck_ab; unsigned short* buck_ba;
    float* out;
    int Eab; int Eba;
};

__device__ inline unsigned short f2bf(float f) {
    unsigned u = __builtin_bit_cast(unsigned, f);
    unsigned r = (u + 0x7FFFu + ((u >> 16) & 1u)) >> 16;
    return (unsigned short)r;
}
__device__ inline float bf2f(unsigned short s) {
    unsigned u = ((unsigned)s) << 16;
    return __builtin_bit_cast(float, u);
}

// ---- K1: W pre-swizzle into MFMA B-fragment layout + counter zero ---------
//   Wf[t][c][lane][e]: k = t*32 + (lane>>4)*8 + e, col = c*16 + (lane&15)
__global__ __launch_bounds__(256) void w_prep_k(Params P) {
    int g = blockIdx.x * 256 + threadIdx.x;  // 0..16383
    for (int z = g; z < 3 * NROW; z += 16384) P.cnt_ab[z] = 0;
    const float* W = (g < 8192) ? P.Wa : P.Wb;
    short* Wf = (g < 8192) ? P.WfA : P.WfB;
    int i = g & 8191;
    int l = i & 63;
    int c = (i >> 6) & 7;
    int t = i >> 9;  // 0..15
    int col = c * 16 + (l & 15);
    int kbase = t * 32 + (l >> 4) * 8;
    short8 o;
#pragma unroll
    for (int e = 0; e < 8; ++e) o[e] = (short)f2bf(W[(size_t)(kbase + e) * D_FEAT + col]);
    *(short8*)(Wf + (size_t)i * 8) = o;
}

// ---- K2: fat kernel = dual MFMA GEMM + edge bucketize ---------------------
__global__ __launch_bounds__(256) void edges_gemm_k(Params P, int nblk_g) {
    int blk = blockIdx.x;
    if (blk >= nblk_g) {
        // ---- edge bucketize half: 512 edges/block ----
        int base = (blk - nblk_g) * 512 + threadIdx.x;
#pragma unroll
        for (int q = 0; q < 2; ++q) {
            int g = base + q * 256;
            if (g < P.Eab) {
                int r = P.ab_row[g], c = P.ab_col[g];
                int p = atomicAdd(&P.cnt_ab[r], 1);
                if (p < BCAP) P.buck_ab[(size_t)r * BCAP + p] = (unsigned short)c;
                atomicAdd(&P.degc[c], 1);
            } else if (g < P.Eab + P.Eba) {
                int e = g - P.Eab;
                int r = P.ba_row[e], c = P.ba_col[e];
                int p = atomicAdd(&P.cnt_ba[r], 1);
                if (p < BCAP) P.buck_ba[(size_t)r * BCAP + p] = (unsigned short)c;
            }
        }
        return;
    }
    // ---- MFMA projection half: 16 rows, 4 waves K-split ----
    __shared__ float red[4][16][132];
    const int tid = threadIdx.x;
    const bool isA = (blk < 256);
    const float* x; const short* Wf; const float* bias;
    if (isA) { x = P.xa; Wf = P.WfA; bias = P.ba; }
    else { blk -= 256; x = P.xb; Wf = P.WfB; bias = P.bb; }
    const int row0 = blk * 16;
    const int w = tid >> 6;
    const int l = tid & 63;
    const int lr = l & 15;
    const int lk = l >> 4;

    f32x4 acc[8];
#pragma unroll
    for (int c = 0; c < 8; ++c) acc[c] = (f32x4){0.f, 0.f, 0.f, 0.f};

    // hoist ALL x loads (8 independent float4 = 8 outstanding HBM loads)
    const float* xrow = x + (size_t)(row0 + lr) * F_IN;
    float4 xf[8];
#pragma unroll
    for (int ks = 0; ks < 4; ++ks) {
        const int k0 = (w * 4 + ks) * 32 + lk * 8;
        xf[2 * ks]     = *(const float4*)(xrow + k0);
        xf[2 * ks + 1] = *(const float4*)(xrow + k0 + 4);
    }

#pragma unroll
    for (int ks = 0; ks < 4; ++ks) {
        const int t = w * 4 + ks;
        float4 xf0 = xf[2 * ks];
        float4 xf1 = xf[2 * ks + 1];
        short8 afr;
        afr[0] = (short)f2bf(xf0.x); afr[1] = (short)f2bf(xf0.y);
        afr[2] = (short)f2bf(xf0.z); afr[3] = (short)f2bf(xf0.w);
        afr[4] = (short)f2bf(xf1.x); afr[5] = (short)f2bf(xf1.y);
        afr[6] = (short)f2bf(xf1.z); afr[7] = (short)f2bf(xf1.w);
        const short8* wfp = (const short8*)Wf + ((size_t)t * 8 * 64 + l);
#pragma unroll
        for (int c = 0; c < 8; ++c) {
            short8 bfr = wfp[c * 64];
            acc[c] = __builtin_amdgcn_mfma_f32_16x16x32_bf16(afr, bfr, acc[c], 0, 0, 0);
        }
    }

#pragma unroll
    for (int c = 0; c < 8; ++c)
#pragma unroll
        for (int r = 0; r < 4; ++r)
            red[w][lk * 4 + r][c * 16 + lr] = acc[c][r];
    __syncthreads();

#pragma unroll
    for (int q = 0; q < 2; ++q) {
        int fi = tid * 2 + q;          // 0..511
        int r = fi >> 5;               // 0..15
        int c4 = fi & 31;              // float4 col index
        float4 s0 = *(const float4*)&red[0][r][c4 * 4];
        float4 s1 = *(const float4*)&red[1][r][c4 * 4];
        float4 s2 = *(const float4*)&red[2][r][c4 * 4];
        float4 s3 = *(const float4*)&red[3][r][c4 * 4];
        float4 bv = ((const float4*)bias)[c4];
        float ox = fmaxf(s0.x + s1.x + s2.x + s3.x + bv.x, 0.0f);
        float oy = fmaxf(s0.y + s1.y + s2.y + s3.y + bv.y, 0.0f);
        float oz = fmaxf(s0.z + s1.z + s2.z + s3.z + bv.z, 0.0f);
        float ow = fmaxf(s0.w + s1.w + s2.w + s3.w + bv.w, 0.0f);
        if (isA) {
            ushort4v ob;
            ob[0] = f2bf(ox); ob[1] = f2bf(oy); ob[2] = f2bf(oz); ob[3] = f2bf(ow);
            *(ushort4v*)(P.ha_bf + (size_t)(row0 + r) * D_FEAT + c4 * 4) = ob;
        } else {
            float4 o; o.x = ox; o.y = oy; o.z = oz; o.w = ow;
            ((float4*)(P.hb + (size_t)(row0 + r) * D_FEAT))[c4] = o;
        }
    }
}

// 16 bf16-pair gathers accumulated into (ax, ay)
#define GATHER8(CBASE)                                                        \
    {                                                                         \
        int c0 = cols[CBASE],     c1 = cols[CBASE + 1];                       \
        int c2 = cols[CBASE + 2], c3 = cols[CBASE + 3];                       \
        int c4 = cols[CBASE + 4], c5 = cols[CBASE + 5];                       \
        int c6 = cols[CBASE + 6], c7 = cols[CBASE + 7];                       \
        unsigned v0 = s2[(size_t)c0 * 64 + lane];                             \
        unsigned v1 = s2[(size_t)c1 * 64 + lane];                             \
        unsigned v2 = s2[(size_t)c2 * 64 + lane];                             \
        unsigned v3 = s2[(size_t)c3 * 64 + lane];                             \
        unsigned v4 = s2[(size_t)c4 * 64 + lane];                             \
        unsigned v5 = s2[(size_t)c5 * 64 + lane];                             \
        unsigned v6 = s2[(size_t)c6 * 64 + lane];                             \
        unsigned v7 = s2[(size_t)c7 * 64 + lane];                             \
        ax += (bf2f((unsigned short)v0) + bf2f((unsigned short)v1)) +         \
              (bf2f((unsigned short)v2) + bf2f((unsigned short)v3)) +         \
              ((bf2f((unsigned short)v4) + bf2f((unsigned short)v5)) +        \
               (bf2f((unsigned short)v6) + bf2f((unsigned short)v7)));        \
        ay += (bf2f((unsigned short)(v0 >> 16)) + bf2f((unsigned short)(v1 >> 16))) + \
              (bf2f((unsigned short)(v2 >> 16)) + bf2f((unsigned short)(v3 >> 16))) + \
              ((bf2f((unsigned short)(v4 >> 16)) + bf2f((unsigned short)(v5 >> 16))) + \
               (bf2f((unsigned short)(v6 >> 16)) + bf2f((unsigned short)(v7 >> 16)))); \
    }

// ---- K3: u[r] = (1/deg[r] or 0) * sum_{c in B-row r} ha_bf[c] + hb[r] -----
// one wave per row; lane owns feats {2*lane, 2*lane+1}; writes u as bf16 pair.
// 16-deep unroll; uniform loads hoisted ahead of the gather loop.
__global__ __launch_bounds__(256) void gather_u_k(Params P) {
    int r = blockIdx.x * 4 + (threadIdx.x >> 6);
    if (r >= NROW) return;
    int lane = threadIdx.x & 63;
    int ncb = P.cnt_ba[r];                 // raw count (true B-row degree)
    int dgc = P.degc[r];                   // in flight with gathers
    float2 hbv = ((const float2*)P.hb)[(size_t)r * 64 + lane];  // in flight
    int n = ncb > BCAP ? BCAP : ncb;
    const unsigned short* cols = P.buck_ba + (size_t)r * BCAP;
    const unsigned* s2 = (const unsigned*)P.ha_bf;  // 2 bf16 per unsigned
    float ax = 0.0f, ay = 0.0f;
    int e = 0;
    for (; e + 15 < n; e += 16) { GATHER8(e) GATHER8(e + 8) }
    for (; e + 3 < n; e += 4) {
        int c0 = cols[e], c1 = cols[e + 1], c2 = cols[e + 2], c3 = cols[e + 3];
        unsigned v0 = s2[(size_t)c0 * 64 + lane];
        unsigned v1 = s2[(size_t)c1 * 64 + lane];
        unsigned v2 = s2[(size_t)c2 * 64 + lane];
        unsigned v3 = s2[(size_t)c3 * 64 + lane];
        ax += (bf2f((unsigned short)v0) + bf2f((unsigned short)v1)) +
              (bf2f((unsigned short)v2) + bf2f((unsigned short)v3));
        ay += (bf2f((unsigned short)(v0 >> 16)) + bf2f((unsigned short)(v1 >> 16))) +
              (bf2f((unsigned short)(v2 >> 16)) + bf2f((unsigned short)(v3 >> 16)));
    }
    for (; e < n; ++e) {
        unsigned v = s2[(size_t)cols[e] * 64 + lane];
        ax += bf2f((unsigned short)v);
        ay += bf2f((unsigned short)(v >> 16));
    }
    float dgf = (float)(dgc + ncb);
    float inv = dgf > 0.0f ? 1.0f / dgf : 0.0f;
    float ux = ax * inv + hbv.x;
    float uy = ay * inv + hbv.y;
    P.u_bf[(size_t)r * 64 + lane] = (unsigned)f2bf(ux) | ((unsigned)f2bf(uy) << 16);
}

// ---- K4: out[r] = sum_{c in A-row r} u_bf[c]  (f32 output) ----------------
__global__ __launch_bounds__(256) void gather_out_k(Params P) {
    int r = blockIdx.x * 4 + (threadIdx.x >> 6);
    if (r >= NROW) return;
    int lane = threadIdx.x & 63;
    int n = P.cnt_ab[r];
    if (n > BCAP) n = BCAP;
    const unsigned short* cols = P.buck_ab + (size_t)r * BCAP;
    const unsigned* s2 = P.u_bf;
    float ax = 0.0f, ay = 0.0f;
    int e = 0;
    for (; e + 15 < n; e += 16) { GATHER8(e) GATHER8(e + 8) }
    for (; e + 3 < n; e += 4) {
        int c0 = cols[e], c1 = cols[e + 1], c2 = cols[e + 2], c3 = cols[e + 3];
        unsigned v0 = s2[(size_t)c0 * 64 + lane];
        unsigned v1 = s2[(size_t)c1 * 64 + lane];
        unsigned v2 = s2[(size_t)c2 * 64 + lane];
        unsigned v3 = s2[(size_t)c3 * 64 + lane];
        ax += (bf2f((unsigned short)v0) + bf2f((unsigned short)v1)) +
              (bf2f((unsigned short)v2) + bf2f((unsigned short)v3));
        ay += (bf2f((unsigned short)(v0 >> 16)) + bf2f((unsigned short)(v1 >> 16))) +
              (bf2f((unsigned short)(v2 >> 16)) + bf2f((unsigned short)(v3 >> 16)));
    }
    for (; e < n; ++e) {
        unsigned v = s2[(size_t)cols[e] * 64 + lane];
        ax += bf2f((unsigned short)v);
        ay += bf2f((unsigned short)(v >> 16));
    }
    float2 o; o.x = ax; o.y = ay;
    ((float2*)P.out)[(size_t)r * 64 + lane] = o;
}

extern "C" void kernel_launch(void* const* d_in, const int* in_sizes, int n_in,
                              void* d_out, int out_size, void* d_ws, size_t ws_size,
                              hipStream_t stream) {
    const float* x_a = (const float*)d_in[0];
    const float* x_b = (const float*)d_in[1];
    const float* W_a = (const float*)d_in[2];
    const float* b_a = (const float*)d_in[3];
    const float* W_b = (const float*)d_in[4];
    const float* b_b = (const float*)d_in[5];
    const int* ei_ab = (const int*)d_in[6];
    const int* ei_ba = (const int*)d_in[7];

    const int D = in_sizes[3];            // 128
    const int Fa = in_sizes[2] / D;       // 512
    const int Na = in_sizes[0] / Fa;      // 4096
    const int Fb = in_sizes[4] / D;       // 512
    const int Nb = in_sizes[1] / Fb;      // 4096
    const int Eab = in_sizes[6] / 2;      // 131072
    const int Eba = in_sizes[7] / 2;      // 131072

    // ---- workspace layout ----
    char* p = (char*)d_ws;
    unsigned short* ha_bf = (unsigned short*)p; p += (size_t)Na * D * 2;  // 1 MB
    float* h_b = (float*)p; p += (size_t)Nb * D * 4;                      // 2 MB
    unsigned* u_bf = (unsigned*)p; p += (size_t)Nb * (D / 2) * 4;         // 1 MB
    unsigned short* buck_ab = (unsigned short*)p; p += (size_t)Na * BCAP * 2;  // 2 MB
    unsigned short* buck_ba = (unsigned short*)p; p += (size_t)Nb * BCAP * 2;  // 2 MB
    short* WfA = (short*)p; p += (size_t)Fa * D * 2;                      // 128 KB
    short* WfB = (short*)p; p += (size_t)Fb * D * 2;
    int* cnt_ab = (int*)p; p += (size_t)Na * 4;                           // zeroed in K1
    int* cnt_ba = (int*)p; p += (size_t)Nb * 4;
    int* degc   = (int*)p; p += (size_t)Nb * 4;

    Params P;
    P.xa = x_a; P.Wa = W_a; P.ba = b_a;
    P.xb = x_b; P.Wb = W_b; P.bb = b_b;
    P.ab_row = ei_ab; P.ab_col = ei_ab + Eab;
    P.ba_row = ei_ba; P.ba_col = ei_ba + Eba;
    P.WfA = WfA; P.WfB = WfB;
    P.ha_bf = ha_bf; P.hb = h_b; P.u_bf = u_bf;
    P.cnt_ab = cnt_ab; P.cnt_ba = cnt_ba; P.degc = degc;
    P.buck_ab = buck_ab; P.buck_ba = buck_ba;
    P.out = (float*)d_out;
    P.Eab = Eab; P.Eba = Eba;

    // K1: zero counters + W -> fragment layout
    w_prep_k<<<64, 256, 0, stream>>>(P);

    // K2: fat kernel — projections (blocks 0..511) + edge bucketize
    int nblk_g = Na / 16 + Nb / 16;                 // 512
    int nEdgeBlk = (Eab + Eba + 511) / 512;         // 512
    edges_gemm_k<<<nblk_g + nEdgeBlk, 256, 0, stream>>>(P, nblk_g);

    // K3: u = d * (B @ h_a) + h_b   (bf16 out)
    gather_u_k<<<(Nb + 3) / 4, 256, 0, stream>>>(P);

    // K4: out = A @ u
    gather_out_k<<<(Na + 3) / 4, 256, 0, stream>>>(P);
}